// Round 4
// baseline (160.965 us; speedup 1.0000x reference)
//
#include <hip/hip_runtime.h>
#include <hip/hip_bf16.h>

#define B_    8
#define S_    4096
#define DIN   512
#define DOUT  64
#define NROWS (B_ * S_)   // 32768

typedef __attribute__((ext_vector_type(8))) short bf16x8;
typedef __attribute__((ext_vector_type(4))) float f32x4;
typedef __attribute__((ext_vector_type(2))) unsigned int u32x2;

typedef const __attribute__((address_space(1))) unsigned int GUI;
typedef __attribute__((address_space(3))) unsigned int LUI;

__device__ __forceinline__ unsigned short f32_to_bf16(float f) {
    union { float f; unsigned int u; } c; c.f = f;
    unsigned int r = (c.u + 0x7FFFu + ((c.u >> 16) & 1u)) >> 16;
    return (unsigned short)r;
}

// ---------------------------------------------------------------------------
// Kernel 1: W_Q|W_K|W_V ([512][64] f32 each) -> Wt2 bf16 in B-frag order:
// Wt2[ks][nf][c15][g][8], ks=k>>5, nf=p*4+(n>>4), c15=n&15, k_local=g*8+j.
// A wave's B-frag load becomes one contiguous 1KB access.
// ---------------------------------------------------------------------------
__global__ void wt_convert(const float* __restrict__ WQ,
                           const float* __restrict__ WK,
                           const float* __restrict__ WV,
                           unsigned short* __restrict__ Wt2) {
    int idx = blockIdx.x * 256 + threadIdx.x;
    if (idx >= 3 * 512 * 16) return;
    int p   = idx / 8192;
    int rem = idx - p * 8192;
    int k   = rem >> 4;
    int n0  = (rem & 15) * 4;
    const float* W = (p == 0) ? WQ : ((p == 1) ? WK : WV);
    float4 v = *(const float4*)(W + k * 64 + n0);
    const int ks = k >> 5, kl = k & 31;
    float vv[4] = {v.x, v.y, v.z, v.w};
#pragma unroll
    for (int r = 0; r < 4; ++r) {
        int n = n0 + r;
        Wt2[(size_t)((ks * 12 + p * 4 + (n >> 4)) * 512) + (n & 15) * 32 + kl] =
            f32_to_bf16(vv[r]);
    }
}

// ---------------------------------------------------------------------------
// Kernel 2: fused QKV projection. x staged through XOR-swizzled LDS with a
// 3-buffer global_load_lds pipeline (coalesced HBM reads, conflict-free
// ds_read_b128 A-frags); B-frags stream contiguously from Wt2 (L2-hot).
// Q pre-scaled by 0.125*log2e (exp2-domain softmax). V stored transposed
// [b][d][s] for the attention kernel's V^T staging.
// ---------------------------------------------------------------------------
__global__ __launch_bounds__(256) void qkv_proj(const float* __restrict__ x,
                                                const unsigned short* __restrict__ Wt2,
                                                unsigned short* __restrict__ QKV) {
    __shared__ alignas(16) float xtile[3][2048];   // 3 x 8KB: [64 rows][8 slots 16B]

    const int tid  = threadIdx.x;
    const int lane = tid & 63;
    const int wq   = tid >> 6;
    const int c15  = lane & 15;
    const int g    = lane >> 4;
    const float* xblk = x + (size_t)blockIdx.x * 64 * DIN;

    // staging geometry: chunk i -> (row=i>>3, dest slot=i&7, src slot ^ row&7)
    const int i0 = wq * 128 + lane, i1 = i0 + 64;
    const int r0 = i0 >> 3, s0 = (i0 & 7) ^ (r0 & 7);
    const int r1 = i1 >> 3, s1 = (i1 & 7) ^ (r1 & 7);

    auto stage = [&](int slot, int ks) {
        const float* xs = xblk + ks * 32;
        char* base = (char*)&xtile[slot][0] + wq * 2048;
        __builtin_amdgcn_global_load_lds((GUI*)(xs + r0 * DIN + s0 * 4), (LUI*)base, 16, 0, 0);
        __builtin_amdgcn_global_load_lds((GUI*)(xs + r1 * DIN + s1 * 4), (LUI*)(base + 1024), 16, 0, 0);
    };
    stage(0, 0);
    stage(1, 1);

    f32x4 acc[12] = {};
    const int arowl = wq * 16 + c15;   // this lane's x row within the block

    int cur = 0;
    for (int ks = 0; ks < 16; ++ks) {
        asm volatile("s_waitcnt vmcnt(2)" ::: "memory");
        asm volatile("s_barrier" ::: "memory");

        const char* xb = (const char*)&xtile[cur][0] + arowl * 128;
        f32x4 a0 = *(const f32x4*)(xb + (((2 * g)     ^ (arowl & 7)) << 4));
        f32x4 a1 = *(const f32x4*)(xb + (((2 * g + 1) ^ (arowl & 7)) << 4));
        union { unsigned w[4]; bf16x8 v; } af;
        asm("v_cvt_pk_bf16_f32 %0, %1, %2" : "=v"(af.w[0]) : "v"(a0[0]), "v"(a0[1]));
        asm("v_cvt_pk_bf16_f32 %0, %1, %2" : "=v"(af.w[1]) : "v"(a0[2]), "v"(a0[3]));
        asm("v_cvt_pk_bf16_f32 %0, %1, %2" : "=v"(af.w[2]) : "v"(a1[0]), "v"(a1[1]));
        asm("v_cvt_pk_bf16_f32 %0, %1, %2" : "=v"(af.w[3]) : "v"(a1[2]), "v"(a1[3]));

        const unsigned short* Bks = Wt2 + (size_t)ks * 12 * 512 + c15 * 32 + g * 8;
#pragma unroll
        for (int nf = 0; nf < 12; ++nf) {
            bf16x8 bf = *(const bf16x8*)(Bks + nf * 512);
            acc[nf] = __builtin_amdgcn_mfma_f32_16x16x32_bf16(af.v, bf, acc[nf], 0, 0, 0);
        }

        {   // prefetch ks+2 (clamped: uniform vmcnt bookkeeping)
            int tn = ks + 2; if (tn > 15) tn = 15;
            int sl = cur + 2; if (sl >= 3) sl -= 3;
            stage(sl, tn);
        }
        cur += 1; if (cur >= 3) cur = 0;
    }
    asm volatile("s_waitcnt vmcnt(0)" ::: "memory");   // drain LDS-DMA pre-endpgm

    const int orow0 = blockIdx.x * 64 + wq * 16 + g * 4;
#pragma unroll
    for (int nf = 0; nf < 12; ++nf) {
        const int p    = nf >> 2;
        const int ncol = (nf & 3) * 16 + c15;
        if (p < 2) {
            unsigned short* outp = QKV + (size_t)p * NROWS * DOUT;
            // Q: fold 1/sqrt(64) * log2(e) so attention works in exp2 domain
            const float sc = (p == 0) ? 0.125f * 1.44269504089f : 1.0f;
#pragma unroll
            for (int r = 0; r < 4; ++r)
                outp[(size_t)(orow0 + r) * DOUT + ncol] = f32_to_bf16(acc[nf][r] * sc);
        } else {
            // V^T[b][ncol][srow..srow+3], 4 bf16 packed into one 8B store
            const int bb   = orow0 >> 12;
            const int srow = orow0 & 4095;
            union { unsigned short s[4]; u32x2 d; } pk;
#pragma unroll
            for (int r = 0; r < 4; ++r) pk.s[r] = f32_to_bf16(acc[nf][r]);
            *(u32x2*)(QKV + (size_t)2 * NROWS * DOUT +
                      ((size_t)bb * DOUT + ncol) * S_ + srow) = pk.d;
        }
    }
}

// ---------------------------------------------------------------------------
// Kernel 3: causal flash attention, S^T/O^T formulation.
// Work-paired grid: bid<256 -> heavy tile t=63-(bid>>3), bid>=256 -> light
// t=(bid-256)>>3; co-resident pairs sum to a constant 65 KV-tiles per CU.
// ---------------------------------------------------------------------------
__global__ __launch_bounds__(256) void attn_fwd(const unsigned short* __restrict__ QKV,
                                                float* __restrict__ out) {
    __shared__ alignas(16) unsigned short k_lds[3][4096]; // K[kv][8 slots], slot^=(kv&7)
    __shared__ alignas(16) unsigned short v_lds[3][4096]; // V^T[d][8 slots], slot^=(d&7)
    __shared__ alignas(16) unsigned short p_lds[4][1024]; // per-wave P[q][kv], swizzled

    const int bid  = blockIdx.x;
    const int half = bid >> 8;            // 0: heavy half, 1: light half
    const int idx  = bid & 255;
    const int b    = idx & 7;             // batch == bid%8 -> per-XCD L2 affinity
    const int tt   = idx >> 3;            // 0..31
    const int t    = half ? tt : 63 - tt; // paired: work(p) + work(p+256) = 65
    const int q0   = t * 64;
    const int tid  = threadIdx.x;
    const int lane = tid & 63;
    const int wq   = tid >> 6;
    const int c15  = lane & 15;
    const int g    = lane >> 4;

    const unsigned short* Qg  = QKV + (size_t)b * S_ * DOUT;
    const unsigned short* Kg  = QKV + (size_t)NROWS * DOUT + (size_t)b * S_ * DOUT;
    const unsigned short* VTg = QKV + (size_t)2 * NROWS * DOUT + (size_t)b * DOUT * S_;

    // Q as B-operand: lane gives Q[q = q0+wq*16+c15][d = 32*kk + 8*g + j]
    const size_t qoff = (size_t)(q0 + wq * 16 + c15) * DOUT;
    bf16x8 qf0 = *(const bf16x8*)(Qg + qoff + g * 8);
    bf16x8 qf1 = *(const bf16x8*)(Qg + qoff + 32 + g * 8);
    asm volatile("s_waitcnt vmcnt(0)" ::: "memory");  // exact vmcnt bookkeeping

    const int nt = t + 1;

    const int i0 = wq * 128 + lane;
    const int i1 = i0 + 64;
    const int r0 = i0 >> 3, s0 = (i0 & 7) ^ (r0 & 7);
    const int r1 = i1 >> 3, s1 = (i1 & 7) ^ (r1 & 7);

    auto stage = [&](int slot, int tt2) {
        const unsigned short* Kt = Kg + (size_t)tt2 * 64 * DOUT;
        const unsigned short* Vt = VTg + tt2 * 64;           // column offset in [d][s]
        char* kbase = (char*)&k_lds[slot][0] + wq * 2048;
        char* vbase = (char*)&v_lds[slot][0] + wq * 2048;
        __builtin_amdgcn_global_load_lds((GUI*)(Kt + r0 * DOUT + s0 * 8), (LUI*)kbase, 16, 0, 0);
        __builtin_amdgcn_global_load_lds((GUI*)(Kt + r1 * DOUT + s1 * 8), (LUI*)(kbase + 1024), 16, 0, 0);
        __builtin_amdgcn_global_load_lds((GUI*)(Vt + (size_t)r0 * S_ + s0 * 8), (LUI*)vbase, 16, 0, 0);
        __builtin_amdgcn_global_load_lds((GUI*)(Vt + (size_t)r1 * S_ + s1 * 8), (LUI*)(vbase + 1024), 16, 0, 0);
    };

    stage(0, 0);
    stage(1, nt > 1 ? 1 : 0);

    f32x4 oacc[4] = {};
    float m_r = -3.0e38f, l_r = 0.f;

    int cur = 0;
    for (int it = 0; it < nt; ++it) {
        asm volatile("s_waitcnt vmcnt(4)" ::: "memory");
        asm volatile("s_barrier" ::: "memory");

        {   // prefetch tile it+2 (clamped so vmcnt arithmetic stays uniform)
            int tn = it + 2; if (tn >= nt) tn = nt - 1;
            int slot = cur + 2; if (slot >= 3) slot -= 3;
            stage(slot, tn);
        }

        const char* kb = (const char*)&k_lds[cur][0];
        const char* vb = (const char*)&v_lds[cur][0];

        // --- S^T = mfma(K, Q): lane holds S^T[kv = 16nf+4g+r][q = c15] ---
        f32x4 s[4];
#pragma unroll
        for (int nf = 0; nf < 4; ++nf) {
            const char* krow = kb + (nf * 16 + c15) * 128;
            bf16x8 kf0 = *(const bf16x8*)(krow + ((g ^ (c15 & 7)) << 4));
            bf16x8 kf1 = *(const bf16x8*)(krow + (((4 + g) ^ (c15 & 7)) << 4));
            f32x4 z = {};
            z = __builtin_amdgcn_mfma_f32_16x16x32_bf16(kf0, qf0, z, 0, 0, 0);
            z = __builtin_amdgcn_mfma_f32_16x16x32_bf16(kf1, qf1, z, 0, 0, 0);
            s[nf] = z;
        }

        // --- causal mask on diagonal tile (k0 == q0): kv_loc > q_loc ---
        if (it == t) {
            const int ql = wq * 16 + c15;
#pragma unroll
            for (int nf = 0; nf < 4; ++nf)
#pragma unroll
                for (int r = 0; r < 4; ++r)
                    if (16 * nf + 4 * g + r > ql) s[nf][r] = -1.0e30f;
        }

        // --- lane-local online softmax in exp2 domain (q = c15) ---
        float mx = s[0][0];
#pragma unroll
        for (int nf = 0; nf < 4; ++nf)
#pragma unroll
            for (int r = 0; r < 4; ++r) mx = fmaxf(mx, s[nf][r]);
        mx = fmaxf(mx, __shfl_xor(mx, 16, 64));
        mx = fmaxf(mx, __shfl_xor(mx, 32, 64));
        const float mnew = fmaxf(m_r, mx);
        const float alpha = exp2f(m_r - mnew);
        m_r = mnew;

        float p[4][4];
        float sum = 0.f;
#pragma unroll
        for (int nf = 0; nf < 4; ++nf)
#pragma unroll
            for (int r = 0; r < 4; ++r) {
                p[nf][r] = exp2f(s[nf][r] - mnew);
                sum += p[nf][r];
            }
        sum += __shfl_xor(sum, 16, 64);
        sum += __shfl_xor(sum, 32, 64);
        l_r = l_r * alpha + sum;
#pragma unroll
        for (int df = 0; df < 4; ++df)
#pragma unroll
            for (int r = 0; r < 4; ++r) oacc[df][r] *= alpha;

        // --- P^T -> bf16 pairs into per-wave swizzled LDS (w = kv/2) ---
#pragma unroll
        for (int nf = 0; nf < 4; ++nf)
#pragma unroll
            for (int pr = 0; pr < 2; ++pr) {
                unsigned pw;
                asm("v_cvt_pk_bf16_f32 %0, %1, %2"
                    : "=v"(pw) : "v"(p[nf][2 * pr]), "v"(p[nf][2 * pr + 1]));
                const int w = 8 * nf + 2 * g + pr;
                *(unsigned*)((char*)&p_lds[wq][0] + c15 * 128 +
                             (((w >> 2) ^ (c15 & 7)) << 4) + (w & 3) * 4) = pw;
            }

        // --- P^T B-frags: lane gives P[q=c15][kv = 32kk + 8g + j] ---
        bf16x8 pf[2];
#pragma unroll
        for (int kk = 0; kk < 2; ++kk)
            pf[kk] = *(const bf16x8*)((char*)&p_lds[wq][0] + c15 * 128 +
                                      (((4 * kk + g) ^ (c15 & 7)) << 4));

        // --- O^T += mfma(V^T, P^T): lane holds O^T[d = 16df+4g+r][q = c15] ---
#pragma unroll
        for (int df = 0; df < 4; ++df) {
            const char* vrow = vb + (df * 16 + c15) * 128;
            bf16x8 vf0 = *(const bf16x8*)(vrow + ((g ^ (c15 & 7)) << 4));
            bf16x8 vf1 = *(const bf16x8*)(vrow + (((4 + g) ^ (c15 & 7)) << 4));
            oacc[df] = __builtin_amdgcn_mfma_f32_16x16x32_bf16(vf0, pf[0], oacc[df], 0, 0, 0);
            oacc[df] = __builtin_amdgcn_mfma_f32_16x16x32_bf16(vf1, pf[1], oacc[df], 0, 0, 0);
        }

        cur += 1; if (cur >= 3) cur = 0;
    }

    // drain all LDS-DMA before this block's LDS can be reallocated
    asm volatile("s_waitcnt vmcnt(0)" ::: "memory");

    // --- epilogue: out[q][d] = O^T[d][q] / l ---
    const float linv = 1.0f / l_r;
    float* outp = out + (size_t)b * S_ * DOUT + (size_t)(q0 + wq * 16 + c15) * DOUT;
#pragma unroll
    for (int df = 0; df < 4; ++df)
#pragma unroll
        for (int r = 0; r < 4; ++r)
            outp[df * 16 + 4 * g + r] = oacc[df][r] * linv;
}

// ---------------------------------------------------------------------------
extern "C" void kernel_launch(void* const* d_in, const int* in_sizes, int n_in,
                              void* d_out, int out_size, void* d_ws, size_t ws_size,
                              hipStream_t stream) {
    const float* x  = (const float*)d_in[0];
    const float* WQ = (const float*)d_in[1];
    const float* WK = (const float*)d_in[2];
    const float* WV = (const float*)d_in[3];

    unsigned short* Wt2 = (unsigned short*)d_ws;   // 192 KB, B-frag order
    unsigned short* QKV = Wt2 + 192 * 512;         // 12 MB: Q | K | V^T

    wt_convert<<<96, 256, 0, stream>>>(WQ, WK, WV, Wt2);
    qkv_proj<<<512, 256, 0, stream>>>(x, Wt2, QKV);
    attn_fwd<<<512, 256, 0, stream>>>(QKV, (float*)d_out);
}

// Round 6
// 96.185 us; speedup vs baseline: 1.6735x; 1.6735x over previous
//
#include <hip/hip_runtime.h>
#include <hip/hip_bf16.h>

#define B_    8
#define S_    4096
#define DIN   512
#define DOUT  64
#define NROWS (B_ * S_)   // 32768

typedef __attribute__((ext_vector_type(8))) short bf16x8;
typedef __attribute__((ext_vector_type(4))) float f32x4;
typedef __attribute__((ext_vector_type(2))) unsigned int u32x2;

typedef const __attribute__((address_space(1))) unsigned int GUI;
typedef __attribute__((address_space(3))) unsigned int LUI;

__device__ __forceinline__ unsigned short f32_to_bf16(float f) {
    union { float f; unsigned int u; } c; c.f = f;
    unsigned int r = (c.u + 0x7FFFu + ((c.u >> 16) & 1u)) >> 16;
    return (unsigned short)r;
}

// Rule-18 fence: all outstanding LDS ops of this wave COMPLETE here, and the
// scheduler may not move anything across. Required before a barrier that
// hands an LDS buffer back to DMA writers (ds_read issued pre-barrier could
// otherwise still be in the LDS queue when another wave's global_load_lds
// write to the same bytes lands -> timing-dependent corruption).
#define LDS_READS_DONE_FENCE() do {                                   \
    asm volatile("s_waitcnt lgkmcnt(0)" ::: "memory");                \
    __builtin_amdgcn_sched_barrier(0);                                \
} while (0)

// ---------------------------------------------------------------------------
// Kernel 1: W_Q|W_K|W_V ([512][64] f32 each) -> Wt2 bf16 in B-frag order:
// Wt2[ks][nf][c15][kl], ks=k>>5, nf=p*4+(n>>4), c15=n&15, kl=k&31.
// Per-ks slice is 12KB contiguous -> stageable with linear global_load_lds.
// ---------------------------------------------------------------------------
__global__ void wt_convert(const float* __restrict__ WQ,
                           const float* __restrict__ WK,
                           const float* __restrict__ WV,
                           unsigned short* __restrict__ Wt2) {
    int idx = blockIdx.x * 256 + threadIdx.x;
    if (idx >= 3 * 512 * 16) return;
    int p   = idx / 8192;
    int rem = idx - p * 8192;
    int k   = rem >> 4;
    int n0  = (rem & 15) * 4;
    const float* W = (p == 0) ? WQ : ((p == 1) ? WK : WV);
    float4 v = *(const float4*)(W + k * 64 + n0);
    const int ks = k >> 5, kl = k & 31;
    float vv[4] = {v.x, v.y, v.z, v.w};
#pragma unroll
    for (int r = 0; r < 4; ++r) {
        int n = n0 + r;
        Wt2[(size_t)((ks * 12 + p * 4 + (n >> 4)) * 512) + (n & 15) * 32 + kl] =
            f32_to_bf16(vv[r]);
    }
}

// ---------------------------------------------------------------------------
// Kernel 2: fused QKV projection. Grid 1024 x 256thr; block = 32 x-rows.
// Waves 0/1: rows 0-15/16-31, nf 0-5; waves 2/3: same rows, nf 6-11.
// BOTH x-tile (4KB, swizzled) and W-slice (12KB, linear) staged per-ks via
// global_load_lds -> uniform 4 insts/thread/iter -> clean vmcnt(4) pipeline.
// 2-buffer, two barriers per iter. Q pre-scaled 0.125*log2e; V stored
// transposed [b][d][s].
// ---------------------------------------------------------------------------
__global__ __launch_bounds__(256) void qkv_proj(const float* __restrict__ x,
                                                const unsigned short* __restrict__ Wt2,
                                                unsigned short* __restrict__ QKV) {
    __shared__ alignas(16) float          xtile[2][1024];  // [32 rows][8 slots], swz
    __shared__ alignas(16) unsigned short btile[2][6144];  // [nf][c15][kl] linear

    const int tid  = threadIdx.x;
    const int lane = tid & 63;
    const int wq   = tid >> 6;
    const int c15  = lane & 15;
    const int g    = lane >> 4;
    const float* xblk = x + (size_t)blockIdx.x * 32 * DIN;

    const int rw     = (wq & 1) * 16 + c15;   // this lane's A row (0..31)
    const int nfbase = (wq >> 1) * 6;         // this wave's nf group

    // x staging geometry: chunk = wq*64+lane -> row=chunk>>3, slot=(chunk&7)^(row&7)
    const int xrow = wq * 8 + (lane >> 3);
    const int xsl  = (lane & 7) ^ (xrow & 7);

    auto stage = [&](int slot, int ks) {
        __builtin_amdgcn_global_load_lds((GUI*)(xblk + ks * 32 + xrow * DIN + xsl * 4),
                                         (LUI*)((char*)&xtile[slot][0] + wq * 1024), 16, 0, 0);
        const unsigned short* Bs = Wt2 + (size_t)ks * 6144;
#pragma unroll
        for (int j = 0; j < 3; ++j)
            __builtin_amdgcn_global_load_lds((GUI*)(Bs + (j * 256 + tid) * 8),
                                             (LUI*)((char*)&btile[slot][0] + j * 4096 + wq * 1024),
                                             16, 0, 0);
    };
    stage(0, 0);
    stage(1, 1);

    f32x4 acc[6] = {};

    int cur = 0;
    for (int ks = 0; ks < 16; ++ks) {
        asm volatile("s_waitcnt vmcnt(4)" ::: "memory");
        asm volatile("s_barrier" ::: "memory");

        const char* xb = (const char*)&xtile[cur][0] + rw * 128;
        f32x4 a0 = *(const f32x4*)(xb + (((2 * g)     ^ (rw & 7)) << 4));
        f32x4 a1 = *(const f32x4*)(xb + (((2 * g + 1) ^ (rw & 7)) << 4));
        union { unsigned w[4]; bf16x8 v; } af;
        asm("v_cvt_pk_bf16_f32 %0, %1, %2" : "=v"(af.w[0]) : "v"(a0[0]), "v"(a0[1]));
        asm("v_cvt_pk_bf16_f32 %0, %1, %2" : "=v"(af.w[1]) : "v"(a0[2]), "v"(a0[3]));
        asm("v_cvt_pk_bf16_f32 %0, %1, %2" : "=v"(af.w[2]) : "v"(a1[0]), "v"(a1[1]));
        asm("v_cvt_pk_bf16_f32 %0, %1, %2" : "=v"(af.w[3]) : "v"(a1[2]), "v"(a1[3]));

        const char* bb = (const char*)&btile[cur][0] + c15 * 64 + g * 16;
#pragma unroll
        for (int n = 0; n < 6; ++n) {
            bf16x8 bf = *(const bf16x8*)(bb + (nfbase + n) * 1024);
            acc[n] = __builtin_amdgcn_mfma_f32_16x16x32_bf16(af.v, bf, acc[n], 0, 0, 0);
        }

        LDS_READS_DONE_FENCE();                   // reads of buf[cur] complete
        asm volatile("s_barrier" ::: "memory");   // ...block-wide
        {
            int tn = ks + 2; if (tn > 15) tn = 15;
            stage(cur, tn);                       // overwrite cur with ks+2
        }
        cur ^= 1;
    }
    asm volatile("s_waitcnt vmcnt(0)" ::: "memory");   // drain LDS-DMA pre-endpgm

    const int orow0 = blockIdx.x * 32 + (wq & 1) * 16 + g * 4;
#pragma unroll
    for (int n = 0; n < 6; ++n) {
        const int nfg  = nfbase + n;
        const int p    = nfg >> 2;
        const int ncol = (nfg & 3) * 16 + c15;
        if (p < 2) {
            unsigned short* outp = QKV + (size_t)p * NROWS * DOUT;
            const float sc = (p == 0) ? 0.125f * 1.44269504089f : 1.0f;
#pragma unroll
            for (int r = 0; r < 4; ++r)
                outp[(size_t)(orow0 + r) * DOUT + ncol] = f32_to_bf16(acc[n][r] * sc);
        } else {
            const int bb2  = orow0 >> 12;
            const int srow = orow0 & 4095;
            union { unsigned short s[4]; u32x2 d; } pk;
#pragma unroll
            for (int r = 0; r < 4; ++r) pk.s[r] = f32_to_bf16(acc[n][r]);
            *(u32x2*)(QKV + (size_t)2 * NROWS * DOUT +
                      ((size_t)bb2 * DOUT + ncol) * S_ + srow) = pk.d;
        }
    }
}

// ---------------------------------------------------------------------------
// Kernel 3: causal flash attention, S^T/O^T, split-KV.
// Grid 768 = 8 batches x 96: i<32 -> (t=32+i, tiles 0..31, partial c=0);
// 32<=i<64 -> (t=63-(i-32), tiles 32..t, partial c=1, diag);
// i>=64 -> (t=95-i, tiles 0..t, direct write, diag). Descending work order.
// 2-buffer LDS (40KB -> 4 blocks/CU), 2 barriers + vmcnt(4) per iter.
// ---------------------------------------------------------------------------
__global__ __launch_bounds__(256) void attn_fwd(const unsigned short* __restrict__ QKV,
                                                float* __restrict__ out,
                                                float* __restrict__ part) {
    __shared__ alignas(16) unsigned short k_lds[2][4096]; // K[kv][8 slots], slot^=(kv&7)
    __shared__ alignas(16) unsigned short v_lds[2][4096]; // V^T[d][8 slots], slot^=(d&7)
    __shared__ alignas(16) unsigned short p_lds[4][1024]; // per-wave P, swizzled

    const int bid = blockIdx.x;
    const int b   = bid & 7;              // batch == bid%8 -> per-XCD L2 affinity
    const int i   = bid >> 3;             // 0..95
    int t, tile_lo, tile_cnt, cidx;
    bool is_partial;
    if (i < 32)      { t = 32 + i;        tile_lo = 0;  tile_cnt = 32;     cidx = 0; is_partial = true; }
    else if (i < 64) { t = 63 - (i - 32); tile_lo = 32; tile_cnt = t - 31; cidx = 1; is_partial = true; }
    else             { t = 95 - i;        tile_lo = 0;  tile_cnt = t + 1;  cidx = 0; is_partial = false; }
    const bool do_diag = (tile_lo + tile_cnt - 1 == t);
    const int q0 = t * 64;

    const int tid  = threadIdx.x;
    const int lane = tid & 63;
    const int wq   = tid >> 6;
    const int c15  = lane & 15;
    const int g    = lane >> 4;

    const unsigned short* Qg  = QKV + (size_t)b * S_ * DOUT;
    const unsigned short* Kg  = QKV + (size_t)NROWS * DOUT + (size_t)b * S_ * DOUT;
    const unsigned short* VTg = QKV + (size_t)2 * NROWS * DOUT + (size_t)b * DOUT * S_;

    const size_t qoff = (size_t)(q0 + wq * 16 + c15) * DOUT;
    bf16x8 qf0 = *(const bf16x8*)(Qg + qoff + g * 8);
    bf16x8 qf1 = *(const bf16x8*)(Qg + qoff + 32 + g * 8);
    asm volatile("s_waitcnt vmcnt(0)" ::: "memory");  // exact vmcnt bookkeeping

    const int i0 = wq * 128 + lane;
    const int i1 = i0 + 64;
    const int r0 = i0 >> 3, s0 = (i0 & 7) ^ (r0 & 7);
    const int r1 = i1 >> 3, s1 = (i1 & 7) ^ (r1 & 7);

    auto stage = [&](int slot, int tg) {
        const unsigned short* Kt = Kg + (size_t)tg * 64 * DOUT;
        const unsigned short* Vt = VTg + tg * 64;
        char* kbase = (char*)&k_lds[slot][0] + wq * 2048;
        char* vbase = (char*)&v_lds[slot][0] + wq * 2048;
        __builtin_amdgcn_global_load_lds((GUI*)(Kt + r0 * DOUT + s0 * 8), (LUI*)kbase, 16, 0, 0);
        __builtin_amdgcn_global_load_lds((GUI*)(Kt + r1 * DOUT + s1 * 8), (LUI*)(kbase + 1024), 16, 0, 0);
        __builtin_amdgcn_global_load_lds((GUI*)(Vt + (size_t)r0 * S_ + s0 * 8), (LUI*)vbase, 16, 0, 0);
        __builtin_amdgcn_global_load_lds((GUI*)(Vt + (size_t)r1 * S_ + s1 * 8), (LUI*)(vbase + 1024), 16, 0, 0);
    };

    stage(0, tile_lo);
    stage(1, tile_lo + (tile_cnt > 1 ? 1 : 0));

    f32x4 oacc[4] = {};
    float m_r = -3.0e38f, l_r = 0.f;

    int cur = 0;
    for (int itl = 0; itl < tile_cnt; ++itl) {
        const int tg = tile_lo + itl;
        asm volatile("s_waitcnt vmcnt(4)" ::: "memory");
        asm volatile("s_barrier" ::: "memory");

        const char* kb = (const char*)&k_lds[cur][0];
        const char* vb = (const char*)&v_lds[cur][0];

        // --- S^T = mfma(K, Q): lane holds S^T[kv = 16nf+4g+r][q = c15] ---
        f32x4 s[4];
#pragma unroll
        for (int nf = 0; nf < 4; ++nf) {
            const char* krow = kb + (nf * 16 + c15) * 128;
            bf16x8 kf0 = *(const bf16x8*)(krow + ((g ^ (c15 & 7)) << 4));
            bf16x8 kf1 = *(const bf16x8*)(krow + (((4 + g) ^ (c15 & 7)) << 4));
            f32x4 z = {};
            z = __builtin_amdgcn_mfma_f32_16x16x32_bf16(kf0, qf0, z, 0, 0, 0);
            z = __builtin_amdgcn_mfma_f32_16x16x32_bf16(kf1, qf1, z, 0, 0, 0);
            s[nf] = z;
        }

        if (do_diag && tg == t) {
            const int ql = wq * 16 + c15;
#pragma unroll
            for (int nf = 0; nf < 4; ++nf)
#pragma unroll
                for (int r = 0; r < 4; ++r)
                    if (16 * nf + 4 * g + r > ql) s[nf][r] = -1.0e30f;
        }

        // --- lane-local online softmax in exp2 domain (q = c15) ---
        float mx = s[0][0];
#pragma unroll
        for (int nf = 0; nf < 4; ++nf)
#pragma unroll
            for (int r = 0; r < 4; ++r) mx = fmaxf(mx, s[nf][r]);
        mx = fmaxf(mx, __shfl_xor(mx, 16, 64));
        mx = fmaxf(mx, __shfl_xor(mx, 32, 64));
        const float mnew = fmaxf(m_r, mx);
        const float alpha = exp2f(m_r - mnew);
        m_r = mnew;

        float p[4][4];
        float sum = 0.f;
#pragma unroll
        for (int nf = 0; nf < 4; ++nf)
#pragma unroll
            for (int r = 0; r < 4; ++r) {
                p[nf][r] = exp2f(s[nf][r] - mnew);
                sum += p[nf][r];
            }
        sum += __shfl_xor(sum, 16, 64);
        sum += __shfl_xor(sum, 32, 64);
        l_r = l_r * alpha + sum;
#pragma unroll
        for (int df = 0; df < 4; ++df)
#pragma unroll
            for (int r = 0; r < 4; ++r) oacc[df][r] *= alpha;

        // --- P^T -> bf16 pairs into per-wave swizzled LDS (w = kv/2) ---
#pragma unroll
        for (int nf = 0; nf < 4; ++nf)
#pragma unroll
            for (int pr = 0; pr < 2; ++pr) {
                unsigned pw;
                asm("v_cvt_pk_bf16_f32 %0, %1, %2"
                    : "=v"(pw) : "v"(p[nf][2 * pr]), "v"(p[nf][2 * pr + 1]));
                const int w = 8 * nf + 2 * g + pr;
                *(unsigned*)((char*)&p_lds[wq][0] + c15 * 128 +
                             (((w >> 2) ^ (c15 & 7)) << 4) + (w & 3) * 4) = pw;
            }

        bf16x8 pf[2];
#pragma unroll
        for (int kk = 0; kk < 2; ++kk)
            pf[kk] = *(const bf16x8*)((char*)&p_lds[wq][0] + c15 * 128 +
                                      (((4 * kk + g) ^ (c15 & 7)) << 4));

        // --- O^T += mfma(V^T, P^T): lane holds O^T[d = 16df+4g+r][q = c15] ---
#pragma unroll
        for (int df = 0; df < 4; ++df) {
            const char* vrow = vb + (df * 16 + c15) * 128;
            bf16x8 vf0 = *(const bf16x8*)(vrow + ((g ^ (c15 & 7)) << 4));
            bf16x8 vf1 = *(const bf16x8*)(vrow + (((4 + g) ^ (c15 & 7)) << 4));
            oacc[df] = __builtin_amdgcn_mfma_f32_16x16x32_bf16(vf0, pf[0], oacc[df], 0, 0, 0);
            oacc[df] = __builtin_amdgcn_mfma_f32_16x16x32_bf16(vf1, pf[1], oacc[df], 0, 0, 0);
        }

        LDS_READS_DONE_FENCE();                   // reads of buf[cur] complete
        asm volatile("s_barrier" ::: "memory");   // ...block-wide
        {
            int tn = itl + 2; if (tn >= tile_cnt) tn = tile_cnt - 1;
            stage(cur, tile_lo + tn);
        }
        cur ^= 1;
    }

    asm volatile("s_waitcnt vmcnt(0)" ::: "memory");   // drain LDS-DMA pre-endpgm

    if (!is_partial) {
        const float linv = 1.0f / l_r;
        float* outp = out + (size_t)b * S_ * DOUT + (size_t)(q0 + wq * 16 + c15) * DOUT;
#pragma unroll
        for (int df = 0; df < 4; ++df)
#pragma unroll
            for (int r = 0; r < 4; ++r)
                outp[df * 16 + 4 * g + r] = oacc[df][r] * linv;
    } else {
        // partial[b][t-32][cidx]: m[64] | l[64] | OT[64][64]
        float* pb = part + (size_t)(((b * 32 + (t - 32)) * 2 + cidx)) * 4224;
        const int ql = wq * 16 + c15;
        if (g == 0) { pb[ql] = m_r; pb[64 + ql] = l_r; }
#pragma unroll
        for (int df = 0; df < 4; ++df)
#pragma unroll
            for (int r = 0; r < 4; ++r)
                pb[128 + (df * 16 + 4 * g + r) * 64 + ql] = oacc[df][r];
    }
}

// ---------------------------------------------------------------------------
// Kernel 4: combine the two KV-chunks for q-tiles t>=32.
// Grid 256 = 8 batches x 32 tz; 256 thr: d = tid&63, q-group = tid>>6.
// ---------------------------------------------------------------------------
__global__ __launch_bounds__(256) void attn_reduce(const float* __restrict__ part,
                                                   float* __restrict__ out) {
    const int b  = blockIdx.x >> 5;
    const int tz = blockIdx.x & 31;
    const int t  = tz + 32;
    const float* p0 = part + (size_t)((b * 32 + tz) * 2 + 0) * 4224;
    const float* p1 = p0 + 4224;
    const int d  = threadIdx.x & 63;
    const int qg = threadIdx.x >> 6;
#pragma unroll
    for (int j = 0; j < 16; ++j) {
        const int q = qg * 16 + j;
        const float m0 = p0[q], l0 = p0[64 + q];
        const float m1 = p1[q], l1 = p1[64 + q];
        const float M  = fmaxf(m0, m1);
        const float e0 = exp2f(m0 - M), e1 = exp2f(m1 - M);
        const float O  = e0 * p0[128 + d * 64 + q] + e1 * p1[128 + d * 64 + q];
        out[(size_t)((b << 12) + (t << 6) + q) * 64 + d] = O / (e0 * l0 + e1 * l1);
    }
}

// ---------------------------------------------------------------------------
extern "C" void kernel_launch(void* const* d_in, const int* in_sizes, int n_in,
                              void* d_out, int out_size, void* d_ws, size_t ws_size,
                              hipStream_t stream) {
    const float* x  = (const float*)d_in[0];
    const float* WQ = (const float*)d_in[1];
    const float* WK = (const float*)d_in[2];
    const float* WV = (const float*)d_in[3];

    unsigned short* Wt2  = (unsigned short*)d_ws;            // 192 KB
    unsigned short* QKV  = Wt2 + 192 * 512;                  // 12 MB: Q | K | V^T
    float*          part = (float*)((char*)d_ws + 12779520); // 8.65 MB partials

    wt_convert<<<96, 256, 0, stream>>>(WQ, WK, WV, Wt2);
    qkv_proj<<<1024, 256, 0, stream>>>(x, Wt2, QKV);
    attn_fwd<<<768, 256, 0, stream>>>(QKV, (float*)d_out, part);
    attn_reduce<<<256, 256, 0, stream>>>(part, (float*)d_out);
}